// Round 3
// baseline (2281.470 us; speedup 1.0000x reference)
//
#include <hip/hip_runtime.h>
#include <math.h>

// UNISURF renderer, MI355X. One wave (64 lanes) per ray; 4 rays per 256-thread
// block. Layer-2 weights are read with WAVE-UNIFORM addresses from global
// memory so the compiler scalarizes them (s_load -> SGPR operand of v_fmac),
// keeping the LDS pipe free. LDS holds only per-ray u/v (broadcast b128) and
// a copy of W2 for the lane-parallel secant evals.

#define HID 128

__device__ __forceinline__ float sigmoidf_(float x) {
    return 1.0f / (1.0f + expf(-x));
}

// Layer2 + heads for one sample at depth d. h1 in 128 VGPRs (static indices).
// Weight operands are wave-uniform global loads -> scalar pipe.
template<bool RGB>
__device__ __forceinline__ void mlp_eval(
    const float* su, const float* sv,                 // LDS (per-ray u, v)
    const float* __restrict__ gW2, const float* __restrict__ gB2,
    const float* __restrict__ gWo, const float* __restrict__ gWc,
    float d, float bo0, float& logit_out, float* rgb_out)
{
    float h1[HID];
#pragma unroll
    for (int k = 0; k < HID; k += 4) {
        float4 u = *reinterpret_cast<const float4*>(su + k);
        float4 v = *reinterpret_cast<const float4*>(sv + k);
        h1[k + 0] = fmaxf(fmaf(d, v.x, u.x), 0.f);
        h1[k + 1] = fmaxf(fmaf(d, v.y, u.y), 0.f);
        h1[k + 2] = fmaxf(fmaf(d, v.z, u.z), 0.f);
        h1[k + 3] = fmaxf(fmaf(d, v.w, u.w), 0.f);
    }
    float lg = 0.f, r0 = 0.f, r1 = 0.f, r2 = 0.f;
#pragma unroll 1   // keep jb rolled: body = 128 uniform dwordx4 loads + 512 FMA
    for (int jb = 0; jb < 32; ++jb) {
        const float4* wq = reinterpret_cast<const float4*>(gW2 + jb * 4); // [k] stride 32 float4
        float a0 = 0.f, a1 = 0.f, a2 = 0.f, a3 = 0.f;
#pragma unroll
        for (int k = 0; k < HID; ++k) {
            const float4 wv = wq[k * 32];          // wave-uniform -> s_load_dwordx4
            a0 = fmaf(h1[k], wv.x, a0);
            a1 = fmaf(h1[k], wv.y, a1);
            a2 = fmaf(h1[k], wv.z, a2);
            a3 = fmaf(h1[k], wv.w, a3);
        }
        const float4 bb = *reinterpret_cast<const float4*>(gB2 + jb * 4);
        const float4 wo = *reinterpret_cast<const float4*>(gWo + jb * 4);
        const float h20 = fmaxf(a0 + bb.x, 0.f);
        const float h21 = fmaxf(a1 + bb.y, 0.f);
        const float h22 = fmaxf(a2 + bb.z, 0.f);
        const float h23 = fmaxf(a3 + bb.w, 0.f);
        lg = fmaf(h20, wo.x, lg);
        lg = fmaf(h21, wo.y, lg);
        lg = fmaf(h22, wo.z, lg);
        lg = fmaf(h23, wo.w, lg);
        if (RGB) {
            const float4* wc4 = reinterpret_cast<const float4*>(gWc + jb * 12);
            const float4 wa = wc4[0], wb = wc4[1], wc = wc4[2];
            r0 = fmaf(h20, wa.x, r0);  r1 = fmaf(h20, wa.y, r1);  r2 = fmaf(h20, wa.z, r2);
            r0 = fmaf(h21, wa.w, r0);  r1 = fmaf(h21, wb.x, r1);  r2 = fmaf(h21, wb.y, r2);
            r0 = fmaf(h22, wb.z, r0);  r1 = fmaf(h22, wb.w, r1);  r2 = fmaf(h22, wc.x, r2);
            r0 = fmaf(h23, wc.y, r0);  r1 = fmaf(h23, wc.z, r1);  r2 = fmaf(h23, wc.w, r2);
        }
    }
    logit_out = lg + bo0;
    if (RGB) { rgb_out[0] = r0; rgb_out[1] = r1; rgb_out[2] = r2; }
}

extern "C" __global__ void __launch_bounds__(256, 2)
unisurf_render_kernel(
    const float* __restrict__ raysDir, const float* __restrict__ raysOrg,
    const float* __restrict__ W1, const float* __restrict__ b1,
    const float* __restrict__ W2, const float* __restrict__ b2,
    const float* __restrict__ Wo, const float* __restrict__ bo,
    const float* __restrict__ Wc, const float* __restrict__ bc,
    const int* __restrict__ itp,
    float* __restrict__ outRGB, float* __restrict__ outD, float* __restrict__ outM,
    int nRays)
{
    __shared__ __align__(16) float sW2[HID * HID];   // [k][j] row-major; secant only
    __shared__ __align__(16) float sB2[HID];
    __shared__ __align__(16) float sWo[HID];
    __shared__ __align__(16) float sU[4][HID];
    __shared__ __align__(16) float sV[4][HID];
    __shared__ __align__(16) float sH1[4][HID];

    const int tid = threadIdx.x;
    {   // stage W2 for the secant path: 4096 float4, coalesced
        const float4* g = reinterpret_cast<const float4*>(W2);
        float4* s = reinterpret_cast<float4*>(sW2);
#pragma unroll
        for (int i = 0; i < 16; ++i) s[tid + i * 256] = g[tid + i * 256];
    }
    if (tid < HID) { sB2[tid] = b2[tid]; sWo[tid] = Wo[tid]; }
    __syncthreads();

    const int w = tid >> 6, lane = tid & 63;
    const int ray = blockIdx.x * 4 + w;
    if (ray >= nRays) return;

    // ---- per-ray setup -----------------------------------------------------
    const float ox = raysOrg[ray * 3 + 0], oy = raysOrg[ray * 3 + 1], oz = raysOrg[ray * 3 + 2];
    const float dx = raysDir[ray * 3 + 0], dy = raysDir[ray * 3 + 1], dz = raysDir[ray * 3 + 2];
    const float nrm = sqrtf(dx * dx + dy * dy + dz * dz);
    const float rdx = dx / nrm, rdy = dy / nrm, rdz = dz / nrm;
    const float bo0 = bo[0];

    float* su = sU[w];
    float* sv = sV[w];
    float* sh = sH1[w];
    for (int k = lane; k < HID; k += 64) {
        const float w1x = W1[k], w1y = W1[HID + k], w1z = W1[2 * HID + k];
        su[k] = ox * w1x + oy * w1y + oz * w1z + b1[k];
        sv[k] = rdx * w1x + rdy * w1y + rdz * w1z;
    }
    asm volatile("s_waitcnt lgkmcnt(0)" ::: "memory");
    __builtin_amdgcn_sched_barrier(0);

    const float STEP = 1.0f / 127.0f;   // linspace(NEAR,FAR,128) step

    // ---- marching: chunk A (steps 0..63) -----------------------------------
    float fA;
    {
        float lg;
        mlp_eval<false>(su, sv, W2, b2, Wo, Wc, 0.8f + (float)lane * STEP, bo0, lg, nullptr);
        fA = sigmoidf_(lg) - 0.5f;
    }
    const float f0 = __shfl(fA, 0);
    const float fAn = __shfl_down(fA, 1);
    const bool crossA = (lane < 63) && (fA * fAn < 0.f);
    const unsigned long long balA = __ballot(crossA);

    int idx = 0; float f_lo = 0.f, f_hi = 0.f; bool haschange = false;
    if (balA) {
        const int l = __ffsll(balA) - 1;
        idx = l; f_lo = __shfl(fA, l); f_hi = __shfl(fA, l + 1); haschange = true;
    } else if (f0 < 0.f) {
        // ---- chunk B (steps 64..127), only if it can still matter ----------
        float fB;
        {
            float lg;
            mlp_eval<false>(su, sv, W2, b2, Wo, Wc, 0.8f + (float)(64 + lane) * STEP, bo0, lg, nullptr);
            fB = sigmoidf_(lg) - 0.5f;
        }
        float fprev = __shfl_up(fB, 1);
        const float fA63 = __shfl(fA, 63);
        if (lane == 0) fprev = fA63;
        const bool crossB = (fprev * fB < 0.f);   // pair s = 63 + lane
        const unsigned long long balB = __ballot(crossB);
        if (balB) {
            const int l = __ffsll(balB) - 1;
            idx = 63 + l; f_lo = __shfl(fprev, l); f_hi = __shfl(fB, l); haschange = true;
        }
    }

    // ---- secant refinement (wave-uniform control) --------------------------
    float d_i;
    bool objmask = false;
    if (f0 >= 0.f) {
        d_i = 0.f;                       // ray starts inside -> mask_zero
    } else if (haschange && (f_lo < 0.f)) {
        float dlo = 0.8f + (float)idx * STEP;
        float dhi = 0.8f + (float)(idx + 1) * STEP;
        float flo = f_lo, fhi = f_hi;
        for (int itn = 0; itn < 8; ++itn) {
            float den = fhi - flo;
            if (fabsf(den) < 1e-12f) den = 1e-12f;
            const float dmid = dlo - flo * (dhi - dlo) / den;
            // lane-parallel MLP eval at dmid: h1 via LDS, j split across lanes
            for (int k = lane; k < HID; k += 64)
                sh[k] = fmaxf(fmaf(dmid, sv[k], su[k]), 0.f);
            asm volatile("s_waitcnt lgkmcnt(0)" ::: "memory");
            __builtin_amdgcn_sched_barrier(0);
            float a0 = 0.f, a1 = 0.f;
#pragma unroll 4
            for (int k = 0; k < HID; ++k) {
                const float hk = sh[k];
                a0 = fmaf(hk, sW2[k * HID + lane], a0);
                a1 = fmaf(hk, sW2[k * HID + lane + 64], a1);
            }
            const float h2a = fmaxf(a0 + sB2[lane], 0.f);
            const float h2b = fmaxf(a1 + sB2[lane + 64], 0.f);
            float part = h2a * sWo[lane] + h2b * sWo[lane + 64];
#pragma unroll
            for (int off = 32; off; off >>= 1) part += __shfl_xor(part, off);
            const float fmid = sigmoidf_(part + bo0) - 0.5f;
            if (fmid < 0.f) { dlo = dmid; flo = fmid; }
            else            { dhi = dmid; fhi = fmid; }
        }
        float den = fhi - flo;
        if (fabsf(den) < 1e-12f) den = 1e-12f;
        d_i = dlo - flo * (dhi - dlo) / den;
        objmask = true;                  // finite & nonzero
    } else {
        d_i = __builtin_inff();          // miss
    }

    // ---- render: 64 samples, lane = sample ---------------------------------
    const int it = itp[0];
    const float delta = fmaxf(0.1f * expf(-2e-5f * (float)it), 0.01f);
    const float dsafe = objmask ? d_i : 1.0f;
    const float dnp = fmaxf(dsafe - delta, 0.8f);
    const float dfp = fminf(dsafe + delta, 1.8f);
    const float t = (float)lane * (1.0f / 63.0f);
    const float depth = objmask ? (dnp * (1.f - t) + dfp * t)
                                : (0.8f * (1.f - t) + 1.8f * t);

    float lg, rgbacc[3];
    mlp_eval<true>(su, sv, W2, b2, Wo, Wc, depth, bo0, lg, rgbacc);
    const float alpha = sigmoidf_(lg);
    float rc[3];
#pragma unroll
    for (int c = 0; c < 3; ++c) {
        const float x = rgbacc[c]
            + rdx * Wc[128 * 3 + c] + rdy * Wc[129 * 3 + c] + rdz * Wc[130 * 3 + c]
            + bc[c];
        rc[c] = sigmoidf_(x);
    }

    // transmittance: exclusive prefix product of (1 - alpha + 1e-6) over lanes
    const float om = 1.f - alpha + 1e-6f;
    float incl = om;
#pragma unroll
    for (int off = 1; off < 64; off <<= 1) {
        const float p = __shfl_up(incl, off);
        if (lane >= off) incl *= p;
    }
    float trans = __shfl_up(incl, 1);
    if (lane == 0) trans = 1.f;
    const float wgt = alpha * trans;

    float s0 = wgt * rc[0], s1 = wgt * rc[1], s2 = wgt * rc[2], sd = wgt * depth;
#pragma unroll
    for (int off = 32; off; off >>= 1) {
        s0 += __shfl_xor(s0, off);
        s1 += __shfl_xor(s1, off);
        s2 += __shfl_xor(s2, off);
        sd += __shfl_xor(sd, off);
    }
    if (lane == 0) {
        outRGB[ray * 3 + 0] = s0;
        outRGB[ray * 3 + 1] = s1;
        outRGB[ray * 3 + 2] = s2;
        outD[ray] = sd;
        outM[ray] = objmask ? 1.f : 0.f;
    }
}

extern "C" void kernel_launch(void* const* d_in, const int* in_sizes, int n_in,
                              void* d_out, int out_size, void* d_ws, size_t ws_size,
                              hipStream_t stream) {
    (void)n_in; (void)out_size; (void)d_ws; (void)ws_size;
    const int R = in_sizes[0] / 3;   // total rays (B*N)
    float* out = reinterpret_cast<float*>(d_out);
    dim3 grid((R + 3) / 4), block(256);
    hipLaunchKernelGGL(unisurf_render_kernel, grid, block, 0, stream,
        (const float*)d_in[0], (const float*)d_in[1], (const float*)d_in[2],
        (const float*)d_in[3], (const float*)d_in[4], (const float*)d_in[5],
        (const float*)d_in[6], (const float*)d_in[7], (const float*)d_in[8],
        (const float*)d_in[9], (const int*)d_in[10],
        out, out + 3 * (size_t)R, out + 4 * (size_t)R, R);
}